// Round 5
// baseline (598.909 us; speedup 1.0000x reference)
//
#include <hip/hip_runtime.h>
#include <hip/hip_bf16.h>

#define NB 1024
#define DM 1024
#define DH 64
#define NH 16
#define NA 4
#define FEPS 1e-6f

typedef __attribute__((ext_vector_type(8))) short s16x8;   // 8 bf16 (4 VGPRs)
typedef __attribute__((ext_vector_type(4))) float f32x4;   // MFMA accumulator

// round-to-nearest-even f32 -> bf16
__device__ __forceinline__ unsigned short f2bf(float f) {
    unsigned u = __builtin_bit_cast(unsigned, f);
    u += 0x7FFFu + ((u >> 16) & 1u);
    return (unsigned short)(u >> 16);
}
__device__ __forceinline__ unsigned pk2(float x, float y) {
    return (unsigned)f2bf(x) | ((unsigned)f2bf(y) << 16);
}

// ---------------- K1: routing (logits, softmax, top-4, head lists) ----------------
__global__ __launch_bounds__(256) void k_route(
    const float* __restrict__ query,
    const float* __restrict__ We,
    const float* __restrict__ be,
    int* __restrict__ cnt,
    int* __restrict__ topi,
    float* __restrict__ topp,
    float* __restrict__ topl,
    int* __restrict__ rows)
{
    int b = blockIdx.x, t = threadIdx.x;
    __shared__ float qs[DM];
    __shared__ float lg[NH];
    __shared__ int   sti[NA];
    __shared__ float stp[NA], stl[NA];
    ((float4*)qs)[t] = ((const float4*)(query + (size_t)b*DM))[t];
    __syncthreads();
    // 16 heads x 16 threads each
    int h = t >> 4, l = t & 15;
    const float* w = We + h*DM;
    float p = 0.f;
    for (int j = l; j < DM; j += 16) p += qs[j]*w[j];
    #pragma unroll
    for (int d = 8; d > 0; d >>= 1) p += __shfl_down(p, d, 16);
    if (l == 0) lg[h] = p + be[h];
    __syncthreads();
    if (t == 0) {
        float mx = lg[0];
        for (int i = 1; i < NH; i++) mx = fmaxf(mx, lg[i]);
        float s = 0.f, e[NH];
        for (int i = 0; i < NH; i++) { e[i] = expf(lg[i]-mx); s += e[i]; }
        float inv = 1.f/s;
        unsigned used = 0;
        for (int a = 0; a < NA; a++) {
            int bi = -1; float bv = -1e30f;
            for (int i = 0; i < NH; i++)
                if (!((used>>i)&1u) && lg[i] > bv) { bv = lg[i]; bi = i; }
            used |= 1u << bi;
            sti[a] = bi; stp[a] = e[bi]*inv; stl[a] = lg[bi];
        }
    }
    __syncthreads();
    if (t < NA) {
        int hh = sti[t];
        topi[b*NA+t] = hh; topp[b*NA+t] = stp[t]; topl[b*NA+t] = stl[t];
        int pos = atomicAdd(&cnt[hh], 1);
        rows[hh*NB + pos] = b*NA + t;   // code = b*4 + slot
    }
}

// ---------------- K2: gathered per-head projection GEMM via bf16 MFMA -------------
__global__ __launch_bounds__(256) void k_proj(
    const float* __restrict__ Xq, const float* __restrict__ Xk, const float* __restrict__ Xv,
    const float* __restrict__ Wq, const float* __restrict__ Wk, const float* __restrict__ Wv,
    const float* __restrict__ bq, const float* __restrict__ bk, const float* __restrict__ bv,
    const int* __restrict__ cnt, const int* __restrict__ rows,
    float* __restrict__ qb, float* __restrict__ kb, float* __restrict__ vb)
{
    int h = blockIdx.x, c = blockIdx.y, pz = blockIdx.z;
    int n = cnt[h];
    int r0 = c*64;
    if (r0 >= n) return;
    int nr = min(64, n - r0);
    const float* X    = pz==0 ? Xq : (pz==1 ? Xk : Xv);
    const float* W    = (pz==0 ? Wq : (pz==1 ? Wk : Wv)) + (size_t)h*DH*DM;
    const float* bias = (pz==0 ? bq : (pz==1 ? bk : bv)) + h*DH;
    float* outp = pz==0 ? qb : (pz==1 ? kb : vb);

    __shared__ __align__(16) unsigned short Af[4*2*64*8];  // 8 KB frag-ordered
    __shared__ __align__(16) unsigned short Bf[4*2*64*8];  // 8 KB frag-ordered
    __shared__ int codes[64];
    int t = threadIdx.x;
    if (t < 64) codes[t] = rows[h*NB + r0 + min(t, nr-1)];
    __syncthreads();

    int lane = t & 63, wv = t >> 6;
    int lr = t >> 2;            // staging row (A) / staging m (W), 0..63
    int ks = (t & 3) * 16;      // 16-k segment within the 64-k tile
    int sA = ks >> 5;           // which 32-k half
    int g0 = (ks >> 3) & 3;     // frag k-group of first 8 elems
    int grp = lr >> 4;          // wr for A / mt for W (same formula)
    int dst0 = ((grp*2 + sA)*64 + (lr & 15) + g0*16) * 8;       // ushort units
    int dst1 = ((grp*2 + sA)*64 + (lr & 15) + (g0+1)*16) * 8;
    const float* srcA = X + (size_t)(codes[lr] >> 2)*DM + ks;
    const float* srcB = W + (size_t)lr*DM + ks;

    f32x4 acc[4] = {};   // acc[mt]
    for (int kt = 0; kt < DM; kt += 64) {
        float4 a0 = ((const float4*)(srcA + kt))[0];
        float4 a1 = ((const float4*)(srcA + kt))[1];
        float4 a2 = ((const float4*)(srcA + kt))[2];
        float4 a3 = ((const float4*)(srcA + kt))[3];
        float4 b0 = ((const float4*)(srcB + kt))[0];
        float4 b1 = ((const float4*)(srcB + kt))[1];
        float4 b2 = ((const float4*)(srcB + kt))[2];
        float4 b3 = ((const float4*)(srcB + kt))[3];
        uint4 pA0 = { pk2(a0.x,a0.y), pk2(a0.z,a0.w), pk2(a1.x,a1.y), pk2(a1.z,a1.w) };
        uint4 pA1 = { pk2(a2.x,a2.y), pk2(a2.z,a2.w), pk2(a3.x,a3.y), pk2(a3.z,a3.w) };
        uint4 pB0 = { pk2(b0.x,b0.y), pk2(b0.z,b0.w), pk2(b1.x,b1.y), pk2(b1.z,b1.w) };
        uint4 pB1 = { pk2(b2.x,b2.y), pk2(b2.z,b2.w), pk2(b3.x,b3.y), pk2(b3.z,b3.w) };
        *(uint4*)(Af + dst0) = pA0;
        *(uint4*)(Af + dst1) = pA1;
        *(uint4*)(Bf + dst0) = pB0;
        *(uint4*)(Bf + dst1) = pB1;
        __syncthreads();
        #pragma unroll
        for (int s = 0; s < 2; s++) {
            s16x8 av = *(const s16x8*)(Af + ((wv*2 + s)*64 + lane)*8);
            #pragma unroll
            for (int mt = 0; mt < 4; mt++) {
                s16x8 bv = *(const s16x8*)(Bf + ((mt*2 + s)*64 + lane)*8);
                acc[mt] = __builtin_amdgcn_mfma_f32_16x16x32_bf16(av, bv, acc[mt], 0, 0, 0);
            }
        }
        __syncthreads();
    }

    // C/D layout: col = lane&15, row = (lane>>4)*4 + reg  (within wave's 16-row tile)
    int rbase = wv*16 + (lane >> 4)*4;
    #pragma unroll
    for (int reg = 0; reg < 4; reg++) {
        int r = rbase + reg;
        if (r < nr) {
            int code = codes[r];
            float* dst = outp + (size_t)code*DH;
            #pragma unroll
            for (int mt = 0; mt < 4; mt++) {
                int m = mt*16 + (lane & 15);
                dst[m] = acc[mt][reg] + bias[m];
            }
        }
    }
}

// ---------------- K3a: per-code scalar/vector prep (one block per code) -----------
// Computes o (-> ob), wp, and per-(b,h) update tables: fd = 1-wp*decay,
// gd = wp*phi_k, vv; writes updated normalizer rows. S read only for the
// 4096 updated (b,h) (67 MB); the 268 MB stream moves to k_apply.
__global__ __launch_bounds__(256) void k_scal(
    const float* __restrict__ matrix,
    const float* __restrict__ normalizer,
    const float* __restrict__ Ww, const float* __restrict__ bw,
    const float* __restrict__ dlog,
    const int* __restrict__ topi, const float* __restrict__ topl,
    const float* __restrict__ qb, const float* __restrict__ kb,
    const float* __restrict__ vb, float* __restrict__ ob,
    float* __restrict__ fd_tab, float* __restrict__ gd_tab,
    float* __restrict__ vv_tab, float* __restrict__ on)
{
    int code = blockIdx.x, t = threadIdx.x;
    int b = code >> 2;
    int h = topi[code];
    int bh = b*NH + h;
    const float* S = matrix + (size_t)bh*(DH*DH);
    __shared__ float st[DH*DH];
    __shared__ float pq[DH], pk[DH], vv[DH], qv[DH], Zs[DH];
    __shared__ float part[256];
    __shared__ float scal2[4];
    if (t < DH) {
        float qq = qb[code*DH + t]; qv[t] = qq;
        float kk = kb[code*DH + t];
        pq[t] = qq > 0.f ? qq + 1.f : expf(qq);   // elu+1
        pk[t] = kk > 0.f ? kk + 1.f : expf(kk);
        vv[t] = vb[code*DH + t];
        Zs[t] = normalizer[(size_t)bh*DH + t];
    }
    #pragma unroll
    for (int j = 0; j < 4; j++)
        ((float4*)st)[t + 256*j] = ((const float4*)S)[t + 256*j];
    __syncthreads();
    // partial column sums of phi_q^T S : 4 d-groups x 64 columns
    {
        int e = t & 63, dg = t >> 6;
        float s = 0.f;
        #pragma unroll
        for (int d = 0; d < 16; d++) s += pq[dg*16 + d] * st[(dg*16+d)*DH + e];
        part[t] = s;
    }
    if (t < 64) {   // wave 0: scalar reductions
        float r1 = pq[t]*pk[t];            // phi_q . phi_k
        float r2 = pq[t]*(Zs[t]+pk[t]);    // phi_q . Z_new
        #pragma unroll
        for (int d = 32; d > 0; d >>= 1) {
            r1 += __shfl_down(r1, d, 64);
            r2 += __shfl_down(r2, d, 64);
        }
        if (t == 0) { scal2[0] = r1; scal2[1] = r2 + FEPS; }
    }
    __syncthreads();
    float pqk = scal2[0], den = scal2[1];
    if (t < 64) {
        float cs = part[t] + part[64+t] + part[128+t] + part[192+t];
        float o = (cs + pqk*vv[t]) / den;
        ob[code*DH + t] = o;
        float r3 = (o + qv[t]) * Ww[h*DH + t];
        #pragma unroll
        for (int d = 32; d > 0; d >>= 1) r3 += __shfl_down(r3, d, 64);
        if (t == 0) {
            float wl = topl[code] + r3 + bw[h];
            scal2[2] = 1.f/(1.f + expf(-wl));   // wp
        }
    }
    __syncthreads();
    float wp = scal2[2];
    if (t < 64) {
        float dec = 1.f/(1.f + expf(-dlog[h*DH + t]));
        float f1 = 1.f - wp*dec;
        float g = wp*pk[t];
        size_t o8 = (size_t)bh*DH + t;
        fd_tab[o8] = f1;
        gd_tab[o8] = g;
        vv_tab[o8] = vv[t];
        on[o8] = Zs[t]*f1 + g;   // Z_out = Z*(1-wp*dec) + wp*phi_k
    }
}

// ---------------- K3b: pure-stream state apply ------------------------------------
// out = S*F + G*v for updated (b,h) (gd != 0), bit-exact copy otherwise.
// A 64-lane wave spans 64 aligned float4 = 4 rows of one (b,h) -> branch is
// wave-uniform. No LDS, no barriers: clean HBM streaming.
__global__ __launch_bounds__(256) void k_apply(
    const float* __restrict__ matrix,
    const float* __restrict__ normalizer,
    const float* __restrict__ fd_tab, const float* __restrict__ gd_tab,
    const float* __restrict__ vv_tab,
    float* __restrict__ om, float* __restrict__ on)
{
    size_t tid = (size_t)blockIdx.x*256 + threadIdx.x;
    size_t nth = (size_t)gridDim.x*256;
    // untouched-normalizer copy (updated rows already written by k_scal)
    const size_t n4 = (size_t)NB*NH*DH/4;      // 262144 float4
    for (size_t i = tid; i < n4; i += nth) {
        float4 g4 = ((const float4*)gd_tab)[i];
        if (g4.x == 0.f)
            ((float4*)on)[i] = ((const float4*)normalizer)[i];
    }
    // matrix stream
    const size_t m4 = (size_t)NB*NH*DH*DH/4;   // 16777216 float4
    for (size_t i = tid; i < m4; i += nth) {
        int bh = (int)(i >> 10);
        int d  = (int)((i >> 4) & 63);
        int e4 = (int)(i & 15);
        float G = gd_tab[bh*DH + d];
        float4 f = ((const float4*)matrix)[i];
        float4 u;
        if (G != 0.f) {
            float F = fd_tab[bh*DH + d];
            float4 v = ((const float4*)vv_tab)[bh*16 + e4];
            u = { f.x*F + G*v.x, f.y*F + G*v.y, f.z*F + G*v.z, f.w*F + G*v.w };
        } else {
            u = f;
        }
        ((float4*)om)[i] = u;
    }
}

// ---------------- K4a: head-grouped output-projection GEMM via bf16 MFMA ----------
__global__ __launch_bounds__(256) void k_mergemm(
    const float* __restrict__ Wo,
    const int* __restrict__ cnt, const int* __restrict__ rows,
    const float* __restrict__ topp, const float* __restrict__ ob,
    float* __restrict__ contrib)
{
    int h = blockIdx.x, rt = blockIdx.y, mtile = blockIdx.z;
    int n = cnt[h];
    int r0 = rt*64;
    if (r0 >= n) return;
    int nr = min(64, n - r0);

    __shared__ __align__(16) unsigned short Af[4*2*64*8];
    __shared__ __align__(16) unsigned short Bf[4*2*64*8];
    __shared__ int codes[64];
    int t = threadIdx.x;
    if (t < 64) codes[t] = rows[h*NB + r0 + min(t, nr-1)];
    __syncthreads();

    int lane = t & 63, wv = t >> 6;
    int lr = t >> 2;
    int es = (t & 3) * 16;
    int sA = es >> 5;
    int g0 = (es >> 3) & 3;
    int grp = lr >> 4;
    int dst0 = ((grp*2 + sA)*64 + (lr & 15) + g0*16) * 8;
    int dst1 = ((grp*2 + sA)*64 + (lr & 15) + (g0+1)*16) * 8;

    {
        int codeA = codes[lr];
        float sc = topp[codeA];
        const float* srcA = ob + (size_t)codeA*DH + es;
        const float* srcB = Wo + (size_t)h*DM*DH + (size_t)(mtile*64 + lr)*DH + es;
        float4 a0 = ((const float4*)srcA)[0];
        float4 a1 = ((const float4*)srcA)[1];
        float4 a2 = ((const float4*)srcA)[2];
        float4 a3 = ((const float4*)srcA)[3];
        float4 b0 = ((const float4*)srcB)[0];
        float4 b1 = ((const float4*)srcB)[1];
        float4 b2 = ((const float4*)srcB)[2];
        float4 b3 = ((const float4*)srcB)[3];
        uint4 pA0 = { pk2(a0.x*sc,a0.y*sc), pk2(a0.z*sc,a0.w*sc),
                      pk2(a1.x*sc,a1.y*sc), pk2(a1.z*sc,a1.w*sc) };
        uint4 pA1 = { pk2(a2.x*sc,a2.y*sc), pk2(a2.z*sc,a2.w*sc),
                      pk2(a3.x*sc,a3.y*sc), pk2(a3.z*sc,a3.w*sc) };
        uint4 pB0 = { pk2(b0.x,b0.y), pk2(b0.z,b0.w), pk2(b1.x,b1.y), pk2(b1.z,b1.w) };
        uint4 pB1 = { pk2(b2.x,b2.y), pk2(b2.z,b2.w), pk2(b3.x,b3.y), pk2(b3.z,b3.w) };
        *(uint4*)(Af + dst0) = pA0;
        *(uint4*)(Af + dst1) = pA1;
        *(uint4*)(Bf + dst0) = pB0;
        *(uint4*)(Bf + dst1) = pB1;
    }
    __syncthreads();

    f32x4 acc[4] = {};
    #pragma unroll
    for (int s = 0; s < 2; s++) {
        s16x8 av = *(const s16x8*)(Af + ((wv*2 + s)*64 + lane)*8);
        #pragma unroll
        for (int mt = 0; mt < 4; mt++) {
            s16x8 bv = *(const s16x8*)(Bf + ((mt*2 + s)*64 + lane)*8);
            acc[mt] = __builtin_amdgcn_mfma_f32_16x16x32_bf16(av, bv, acc[mt], 0, 0, 0);
        }
    }

    int rbase = wv*16 + (lane >> 4)*4;
    int mbase = mtile*64 + (lane & 15);
    #pragma unroll
    for (int reg = 0; reg < 4; reg++) {
        int r = rbase + reg;
        if (r < nr) {
            float* dst = contrib + (size_t)codes[r]*DM + mbase;
            #pragma unroll
            for (int mt = 0; mt < 4; mt++)
                dst[mt*16] = acc[mt][reg];
        }
    }
}

// ---------------- K4b: finalize merged = sum_a contrib[b,a,:] + top_p*bo ---------
__global__ __launch_bounds__(256) void k_finalize(
    const int* __restrict__ topi, const float* __restrict__ topp,
    const float* __restrict__ bo, const float* __restrict__ contrib,
    float* __restrict__ merged)
{
    int b = blockIdx.x, t = threadIdx.x;
    __shared__ float tp[NA];
    __shared__ int   hh[NA];
    if (t < NA) { tp[t] = topp[b*NA+t]; hh[t] = topi[b*NA+t]; }
    __syncthreads();
    float ax = 0.f, ay = 0.f, az = 0.f, aw = 0.f;
    #pragma unroll
    for (int a = 0; a < NA; a++) {
        float4 cv = ((const float4*)(contrib + (size_t)(b*NA + a)*DM))[t];
        float4 w  = ((const float4*)(bo + (size_t)hh[a]*DM))[t];
        float p = tp[a];
        ax += cv.x + p*w.x; ay += cv.y + p*w.y;
        az += cv.z + p*w.z; aw += cv.w + p*w.w;
    }
    float4 u = { ax, ay, az, aw };
    ((float4*)merged)[(size_t)b*(DM/4) + t] = u;
}

extern "C" void kernel_launch(void* const* d_in, const int* in_sizes, int n_in,
                              void* d_out, int out_size, void* d_ws, size_t ws_size,
                              hipStream_t stream)
{
    const float* query  = (const float*)d_in[0];
    const float* key    = (const float*)d_in[1];
    const float* value  = (const float*)d_in[2];
    const float* matrix = (const float*)d_in[3];
    const float* normal = (const float*)d_in[4];
    const float* Wq = (const float*)d_in[5];
    const float* bq = (const float*)d_in[6];
    const float* Wk = (const float*)d_in[7];
    const float* bk = (const float*)d_in[8];
    const float* Wv = (const float*)d_in[9];
    const float* bv = (const float*)d_in[10];
    const float* Wo = (const float*)d_in[11];
    const float* bo = (const float*)d_in[12];
    const float* We = (const float*)d_in[13];
    const float* be = (const float*)d_in[14];
    const float* Ww = (const float*)d_in[15];
    const float* bw = (const float*)d_in[16];
    const float* dlog = (const float*)d_in[17];

    float* ws = (float*)d_ws;
    int*   cnt  = (int*)ws;                  // 16 ints
    int*   topi = (int*)(ws + 16);           // 4096
    float* topp = ws + 16 + 4096;            // 4096
    float* topl = topp + 4096;               // 4096
    int*   rows = (int*)(topl + 4096);       // 16384
    float* qb = (float*)(rows + 16384);      // 262144
    float* kb = qb + 262144;
    float* vb = kb + 262144;
    float* ob = vb + 262144;
    float* contrib = ob + 262144;            // NB*NA*DM = 4M floats (16 MB)
    float* fd_tab = contrib + (size_t)NB*NA*DM;   // NB*NH*DH = 1M floats
    float* gd_tab = fd_tab + (size_t)NB*NH*DH;
    float* vv_tab = gd_tab + (size_t)NB*NH*DH;

    float* out_merged = (float*)d_out;
    float* out_matrix = out_merged + (size_t)NB*DM;
    float* out_norm   = out_matrix + (size_t)NB*NH*DH*DH;

    hipMemsetAsync(cnt, 0, 16*sizeof(int), stream);
    hipMemsetAsync(gd_tab, 0, (size_t)NB*NH*DH*sizeof(float), stream);
    k_route<<<NB, 256, 0, stream>>>(query, We, be, cnt, topi, topp, topl, rows);
    k_proj<<<dim3(NH, NB/64, 3), 256, 0, stream>>>(query, key, value, Wq, Wk, Wv,
                                                   bq, bk, bv, cnt, rows, qb, kb, vb);
    k_scal<<<NB*NA, 256, 0, stream>>>(matrix, normal, Ww, bw, dlog, topi, topl,
                                      qb, kb, vb, ob, fd_tab, gd_tab, vv_tab,
                                      out_norm);
    k_apply<<<2048, 256, 0, stream>>>(matrix, normal, fd_tab, gd_tab, vv_tab,
                                      out_matrix, out_norm);
    k_mergemm<<<dim3(NH, NB/64, DM/64), 256, 0, stream>>>(Wo, cnt, rows, topp, ob,
                                                          contrib);
    k_finalize<<<NB, 256, 0, stream>>>(topi, topp, bo, contrib, out_merged);
}

// Round 6
// 573.532 us; speedup vs baseline: 1.0442x; 1.0442x over previous
//
#include <hip/hip_runtime.h>
#include <hip/hip_bf16.h>

#define NB 1024
#define DM 1024
#define DH 64
#define NH 16
#define NA 4
#define FEPS 1e-6f

typedef __attribute__((ext_vector_type(8))) short s16x8;   // 8 bf16 (4 VGPRs)
typedef __attribute__((ext_vector_type(4))) float f32x4;   // MFMA accumulator

// round-to-nearest-even f32 -> bf16
__device__ __forceinline__ unsigned short f2bf(float f) {
    unsigned u = __builtin_bit_cast(unsigned, f);
    u += 0x7FFFu + ((u >> 16) & 1u);
    return (unsigned short)(u >> 16);
}
__device__ __forceinline__ unsigned pk2(float x, float y) {
    return (unsigned)f2bf(x) | ((unsigned)f2bf(y) << 16);
}

// ---------------- K1: routing (logits, softmax, top-4, head lists) ----------------
__global__ __launch_bounds__(256) void k_route(
    const float* __restrict__ query,
    const float* __restrict__ We,
    const float* __restrict__ be,
    int* __restrict__ cnt,
    int* __restrict__ topi,
    float* __restrict__ topp,
    float* __restrict__ topl,
    int* __restrict__ slot,
    int* __restrict__ rows)
{
    int b = blockIdx.x, t = threadIdx.x;
    __shared__ float qs[DM];
    __shared__ float lg[NH];
    __shared__ int   sti[NA];
    __shared__ float stp[NA], stl[NA];
    ((float4*)qs)[t] = ((const float4*)(query + (size_t)b*DM))[t];
    __syncthreads();
    // 16 heads x 16 threads each
    int h = t >> 4, l = t & 15;
    const float* w = We + h*DM;
    float p = 0.f;
    for (int j = l; j < DM; j += 16) p += qs[j]*w[j];
    #pragma unroll
    for (int d = 8; d > 0; d >>= 1) p += __shfl_down(p, d, 16);
    if (l == 0) lg[h] = p + be[h];
    __syncthreads();
    if (t == 0) {
        float mx = lg[0];
        for (int i = 1; i < NH; i++) mx = fmaxf(mx, lg[i]);
        float s = 0.f, e[NH];
        for (int i = 0; i < NH; i++) { e[i] = expf(lg[i]-mx); s += e[i]; }
        float inv = 1.f/s;
        unsigned used = 0;
        for (int a = 0; a < NA; a++) {
            int bi = -1; float bv = -1e30f;
            for (int i = 0; i < NH; i++)
                if (!((used>>i)&1u) && lg[i] > bv) { bv = lg[i]; bi = i; }
            used |= 1u << bi;
            sti[a] = bi; stp[a] = e[bi]*inv; stl[a] = lg[bi];
        }
    }
    __syncthreads();
    if (t < NA) {
        int hh = sti[t];
        topi[b*NA+t] = hh; topp[b*NA+t] = stp[t]; topl[b*NA+t] = stl[t];
        int pos = atomicAdd(&cnt[hh], 1);
        rows[hh*NB + pos] = b*NA + t;   // code = b*4 + slot
    }
    if (t < NH) {
        int sl = -1;
        #pragma unroll
        for (int a = 0; a < NA; a++) if (sti[a] == t) sl = a;
        slot[b*NH + t] = sl;
    }
}

// ---------------- K2: gathered per-head projection GEMM via bf16 MFMA -------------
// 64 gathered rows x 64 out-dims, K=1024 in 64-wide tiles. 4 waves; wave w owns
// rows [16w,16w+16). LDS in FRAG ORDER so every fragment read is a contiguous,
// conflict-free wave-wide ds_read_b128. Register double-buffer: next tile's
// global loads issue right after the first barrier and retire under the MFMAs.
__global__ __launch_bounds__(256) void k_proj(
    const float* __restrict__ Xq, const float* __restrict__ Xk, const float* __restrict__ Xv,
    const float* __restrict__ Wq, const float* __restrict__ Wk, const float* __restrict__ Wv,
    const float* __restrict__ bq, const float* __restrict__ bk, const float* __restrict__ bv,
    const int* __restrict__ cnt, const int* __restrict__ rows,
    float* __restrict__ qb, float* __restrict__ kb, float* __restrict__ vb)
{
    int h = blockIdx.x, c = blockIdx.y, pz = blockIdx.z;
    int n = cnt[h];
    int r0 = c*64;
    if (r0 >= n) return;
    int nr = min(64, n - r0);
    const float* X    = pz==0 ? Xq : (pz==1 ? Xk : Xv);
    const float* W    = (pz==0 ? Wq : (pz==1 ? Wk : Wv)) + (size_t)h*DH*DM;
    const float* bias = (pz==0 ? bq : (pz==1 ? bk : bv)) + h*DH;
    float* outp = pz==0 ? qb : (pz==1 ? kb : vb);

    __shared__ __align__(16) unsigned short Af[4*2*64*8];  // 8 KB frag-ordered
    __shared__ __align__(16) unsigned short Bf[4*2*64*8];  // 8 KB frag-ordered
    __shared__ int codes[64];
    int t = threadIdx.x;
    if (t < 64) codes[t] = rows[h*NB + r0 + min(t, nr-1)];
    __syncthreads();

    int lane = t & 63, wv = t >> 6;
    int lr = t >> 2;            // staging row (A) / staging m (W), 0..63
    int ks = (t & 3) * 16;      // 16-k segment within the 64-k tile
    int sA = ks >> 5;           // which 32-k half
    int g0 = (ks >> 3) & 3;     // frag k-group of first 8 elems
    int grp = lr >> 4;          // wr for A / mt for W (same formula)
    int dst0 = ((grp*2 + sA)*64 + (lr & 15) + g0*16) * 8;       // ushort units
    int dst1 = ((grp*2 + sA)*64 + (lr & 15) + (g0+1)*16) * 8;
    const float* srcA = X + (size_t)(codes[lr] >> 2)*DM + ks;
    const float* srcB = W + (size_t)lr*DM + ks;

    float4 ca[4], cb[4];
    #pragma unroll
    for (int j = 0; j < 4; j++) {
        ca[j] = ((const float4*)srcA)[j];
        cb[j] = ((const float4*)srcB)[j];
    }

    f32x4 acc[4] = {};   // acc[mt]
    for (int kt = 0; kt < DM; kt += 64) {
        uint4 pA0 = { pk2(ca[0].x,ca[0].y), pk2(ca[0].z,ca[0].w),
                      pk2(ca[1].x,ca[1].y), pk2(ca[1].z,ca[1].w) };
        uint4 pA1 = { pk2(ca[2].x,ca[2].y), pk2(ca[2].z,ca[2].w),
                      pk2(ca[3].x,ca[3].y), pk2(ca[3].z,ca[3].w) };
        uint4 pB0 = { pk2(cb[0].x,cb[0].y), pk2(cb[0].z,cb[0].w),
                      pk2(cb[1].x,cb[1].y), pk2(cb[1].z,cb[1].w) };
        uint4 pB1 = { pk2(cb[2].x,cb[2].y), pk2(cb[2].z,cb[2].w),
                      pk2(cb[3].x,cb[3].y), pk2(cb[3].z,cb[3].w) };
        *(uint4*)(Af + dst0) = pA0;
        *(uint4*)(Af + dst1) = pA1;
        *(uint4*)(Bf + dst0) = pB0;
        *(uint4*)(Bf + dst1) = pB1;
        __syncthreads();
        if (kt + 64 < DM) {   // prefetch next tile; retires under the MFMAs
            #pragma unroll
            for (int j = 0; j < 4; j++) {
                ca[j] = ((const float4*)(srcA + kt + 64))[j];
                cb[j] = ((const float4*)(srcB + kt + 64))[j];
            }
        }
        #pragma unroll
        for (int s = 0; s < 2; s++) {
            s16x8 av = *(const s16x8*)(Af + ((wv*2 + s)*64 + lane)*8);
            #pragma unroll
            for (int mt = 0; mt < 4; mt++) {
                s16x8 bv = *(const s16x8*)(Bf + ((mt*2 + s)*64 + lane)*8);
                acc[mt] = __builtin_amdgcn_mfma_f32_16x16x32_bf16(av, bv, acc[mt], 0, 0, 0);
            }
        }
        __syncthreads();
    }

    // C/D layout: col = lane&15, row = (lane>>4)*4 + reg  (within wave's 16-row tile)
    int rbase = wv*16 + (lane >> 4)*4;
    #pragma unroll
    for (int reg = 0; reg < 4; reg++) {
        int r = rbase + reg;
        if (r < nr) {
            int code = codes[r];
            float* dst = outp + (size_t)code*DH;
            #pragma unroll
            for (int mt = 0; mt < 4; mt++) {
                int m = mt*16 + (lane & 15);
                dst[m] = acc[mt][reg] + bias[m];
            }
        }
    }
}

// ---------------- K3: per-(b,h) state copy or linear-attention update -------------
__global__ __launch_bounds__(256) void k_update(
    const float* __restrict__ matrix,
    const float* __restrict__ normalizer,
    const float* __restrict__ Ww, const float* __restrict__ bw,
    const float* __restrict__ dlog,
    const int* __restrict__ slot, const float* __restrict__ topl,
    const float* __restrict__ qb, const float* __restrict__ kb,
    const float* __restrict__ vb, float* __restrict__ ob,
    float* __restrict__ om, float* __restrict__ on)
{
    int bh = blockIdx.x, t = threadIdx.x;
    const float* S = matrix + (size_t)bh*(DH*DH);
    float* So = om + (size_t)bh*(DH*DH);
    int sl = slot[bh];
    if (sl < 0) {
        // pure copy path (12/16 of all blocks): f32 -> f32
        #pragma unroll
        for (int j = 0; j < 4; j++) {
            int i4 = t + 256*j;
            ((float4*)So)[i4] = ((const float4*)S)[i4];
        }
        if (t < DH)
            on[(size_t)bh*DH + t] = normalizer[(size_t)bh*DH + t];
        return;
    }
    int b = bh >> 4, h = bh & 15;
    int code = b*NA + sl;
    __shared__ float st[DH*DH];
    __shared__ float pq[DH], pk[DH], vv[DH], qv[DH], Zs[DH];
    __shared__ float part[256];
    __shared__ float fd[DH], gd[DH];
    __shared__ float scal[4];
    if (t < DH) {
        float qq = qb[code*DH + t]; qv[t] = qq;
        float kk = kb[code*DH + t];
        pq[t] = qq > 0.f ? qq + 1.f : expf(qq);   // elu+1
        pk[t] = kk > 0.f ? kk + 1.f : expf(kk);
        vv[t] = vb[code*DH + t];
        Zs[t] = normalizer[(size_t)bh*DH + t];
    }
    #pragma unroll
    for (int j = 0; j < 4; j++)
        ((float4*)st)[t + 256*j] = ((const float4*)S)[t + 256*j];
    __syncthreads();
    // partial column sums of phi_q^T S : 4 d-groups x 64 columns
    {
        int e = t & 63, dg = t >> 6;
        float s = 0.f;
        #pragma unroll
        for (int d = 0; d < 16; d++) s += pq[dg*16 + d] * st[(dg*16+d)*DH + e];
        part[t] = s;
    }
    if (t < 64) {   // wave 0: scalar reductions
        float r1 = pq[t]*pk[t];            // phi_q . phi_k
        float r2 = pq[t]*(Zs[t]+pk[t]);    // phi_q . Z_new
        #pragma unroll
        for (int d = 32; d > 0; d >>= 1) {
            r1 += __shfl_down(r1, d, 64);
            r2 += __shfl_down(r2, d, 64);
        }
        if (t == 0) { scal[0] = r1; scal[1] = r2 + FEPS; }
    }
    __syncthreads();
    float pqk = scal[0], den = scal[1];
    if (t < 64) {
        float cs = part[t] + part[64+t] + part[128+t] + part[192+t];
        float o = (cs + pqk*vv[t]) / den;
        ob[code*DH + t] = o;
        float r3 = (o + qv[t]) * Ww[h*DH + t];
        #pragma unroll
        for (int d = 32; d > 0; d >>= 1) r3 += __shfl_down(r3, d, 64);
        if (t == 0) {
            float wl = topl[code] + r3 + bw[h];
            scal[2] = 1.f/(1.f + expf(-wl));   // wp
        }
    }
    __syncthreads();
    float wp = scal[2];
    if (t < 64) {
        float dec = 1.f/(1.f + expf(-dlog[h*DH + t]));
        float f1 = 1.f - wp*dec;
        fd[t] = f1;
        gd[t] = wp*pk[t];
        on[(size_t)bh*DH + t] = Zs[t]*f1 + wp*pk[t];
    }
    __syncthreads();
    #pragma unroll
    for (int j = 0; j < 4; j++) {
        int i4 = t + 256*j;
        int d = i4 >> 4, e0 = (i4 & 15)*4;   // 16 float4 per 64-wide row
        float4 f = ((const float4*)st)[i4];
        float F = fd[d], G = gd[d];
        float4 u = { f.x*F + G*vv[e0],   f.y*F + G*vv[e0+1],
                     f.z*F + G*vv[e0+2], f.w*F + G*vv[e0+3] };
        ((float4*)So)[i4] = u;
    }
}

// ---------------- K4a: head-grouped output-projection GEMM via bf16 MFMA ----------
__global__ __launch_bounds__(256) void k_mergemm(
    const float* __restrict__ Wo,
    const int* __restrict__ cnt, const int* __restrict__ rows,
    const float* __restrict__ topp, const float* __restrict__ ob,
    float* __restrict__ contrib)
{
    int h = blockIdx.x, rt = blockIdx.y, mtile = blockIdx.z;
    int n = cnt[h];
    int r0 = rt*64;
    if (r0 >= n) return;
    int nr = min(64, n - r0);

    __shared__ __align__(16) unsigned short Af[4*2*64*8];
    __shared__ __align__(16) unsigned short Bf[4*2*64*8];
    __shared__ int codes[64];
    int t = threadIdx.x;
    if (t < 64) codes[t] = rows[h*NB + r0 + min(t, nr-1)];
    __syncthreads();

    int lane = t & 63, wv = t >> 6;
    int lr = t >> 2;
    int es = (t & 3) * 16;
    int sA = es >> 5;
    int g0 = (es >> 3) & 3;
    int grp = lr >> 4;
    int dst0 = ((grp*2 + sA)*64 + (lr & 15) + g0*16) * 8;
    int dst1 = ((grp*2 + sA)*64 + (lr & 15) + (g0+1)*16) * 8;

    {
        int codeA = codes[lr];
        float sc = topp[codeA];
        const float* srcA = ob + (size_t)codeA*DH + es;
        const float* srcB = Wo + (size_t)h*DM*DH + (size_t)(mtile*64 + lr)*DH + es;
        float4 a0 = ((const float4*)srcA)[0];
        float4 a1 = ((const float4*)srcA)[1];
        float4 a2 = ((const float4*)srcA)[2];
        float4 a3 = ((const float4*)srcA)[3];
        float4 b0 = ((const float4*)srcB)[0];
        float4 b1 = ((const float4*)srcB)[1];
        float4 b2 = ((const float4*)srcB)[2];
        float4 b3 = ((const float4*)srcB)[3];
        uint4 pA0 = { pk2(a0.x*sc,a0.y*sc), pk2(a0.z*sc,a0.w*sc),
                      pk2(a1.x*sc,a1.y*sc), pk2(a1.z*sc,a1.w*sc) };
        uint4 pA1 = { pk2(a2.x*sc,a2.y*sc), pk2(a2.z*sc,a2.w*sc),
                      pk2(a3.x*sc,a3.y*sc), pk2(a3.z*sc,a3.w*sc) };
        uint4 pB0 = { pk2(b0.x,b0.y), pk2(b0.z,b0.w), pk2(b1.x,b1.y), pk2(b1.z,b1.w) };
        uint4 pB1 = { pk2(b2.x,b2.y), pk2(b2.z,b2.w), pk2(b3.x,b3.y), pk2(b3.z,b3.w) };
        *(uint4*)(Af + dst0) = pA0;
        *(uint4*)(Af + dst1) = pA1;
        *(uint4*)(Bf + dst0) = pB0;
        *(uint4*)(Bf + dst1) = pB1;
    }
    __syncthreads();

    f32x4 acc[4] = {};
    #pragma unroll
    for (int s = 0; s < 2; s++) {
        s16x8 av = *(const s16x8*)(Af + ((wv*2 + s)*64 + lane)*8);
        #pragma unroll
        for (int mt = 0; mt < 4; mt++) {
            s16x8 bv = *(const s16x8*)(Bf + ((mt*2 + s)*64 + lane)*8);
            acc[mt] = __builtin_amdgcn_mfma_f32_16x16x32_bf16(av, bv, acc[mt], 0, 0, 0);
        }
    }

    int rbase = wv*16 + (lane >> 4)*4;
    int mbase = mtile*64 + (lane & 15);
    #pragma unroll
    for (int reg = 0; reg < 4; reg++) {
        int r = rbase + reg;
        if (r < nr) {
            float* dst = contrib + (size_t)codes[r]*DM + mbase;
            #pragma unroll
            for (int mt = 0; mt < 4; mt++)
                dst[mt*16] = acc[mt][reg];
        }
    }
}

// ---------------- K4b: finalize merged = sum_a contrib[b,a,:] + top_p*bo ---------
__global__ __launch_bounds__(256) void k_finalize(
    const int* __restrict__ topi, const float* __restrict__ topp,
    const float* __restrict__ bo, const float* __restrict__ contrib,
    float* __restrict__ merged)
{
    int b = blockIdx.x, t = threadIdx.x;
    __shared__ float tp[NA];
    __shared__ int   hh[NA];
    if (t < NA) { tp[t] = topp[b*NA+t]; hh[t] = topi[b*NA+t]; }
    __syncthreads();
    float ax = 0.f, ay = 0.f, az = 0.f, aw = 0.f;
    #pragma unroll
    for (int a = 0; a < NA; a++) {
        float4 cv = ((const float4*)(contrib + (size_t)(b*NA + a)*DM))[t];
        float4 w  = ((const float4*)(bo + (size_t)hh[a]*DM))[t];
        float p = tp[a];
        ax += cv.x + p*w.x; ay += cv.y + p*w.y;
        az += cv.z + p*w.z; aw += cv.w + p*w.w;
    }
    float4 u = { ax, ay, az, aw };
    ((float4*)merged)[(size_t)b*(DM/4) + t] = u;
}

extern "C" void kernel_launch(void* const* d_in, const int* in_sizes, int n_in,
                              void* d_out, int out_size, void* d_ws, size_t ws_size,
                              hipStream_t stream)
{
    const float* query  = (const float*)d_in[0];
    const float* key    = (const float*)d_in[1];
    const float* value  = (const float*)d_in[2];
    const float* matrix = (const float*)d_in[3];
    const float* normal = (const float*)d_in[4];
    const float* Wq = (const float*)d_in[5];
    const float* bq = (const float*)d_in[6];
    const float* Wk = (const float*)d_in[7];
    const float* bk = (const float*)d_in[8];
    const float* Wv = (const float*)d_in[9];
    const float* bv = (const float*)d_in[10];
    const float* Wo = (const float*)d_in[11];
    const float* bo = (const float*)d_in[12];
    const float* We = (const float*)d_in[13];
    const float* be = (const float*)d_in[14];
    const float* Ww = (const float*)d_in[15];
    const float* bw = (const float*)d_in[16];
    const float* dlog = (const float*)d_in[17];

    float* ws = (float*)d_ws;
    int*   cnt  = (int*)ws;                  // 16 ints
    int*   topi = (int*)(ws + 16);           // 4096
    float* topp = ws + 16 + 4096;            // 4096
    float* topl = topp + 4096;               // 4096
    int*   slot = (int*)(topl + 4096);       // 16384
    int*   rows = slot + 16384;              // 16384
    float* qb = (float*)(rows + 16384);      // 262144
    float* kb = qb + 262144;
    float* vb = kb + 262144;
    float* ob = vb + 262144;
    float* contrib = ob + 262144;            // NB*NA*DM = 4M floats (16 MB)

    float* out_merged = (float*)d_out;
    float* out_matrix = out_merged + (size_t)NB*DM;
    float* out_norm   = out_matrix + (size_t)NB*NH*DH*DH;

    hipMemsetAsync(cnt, 0, 16*sizeof(int), stream);
    k_route<<<NB, 256, 0, stream>>>(query, We, be, cnt, topi, topp, topl, slot, rows);
    k_proj<<<dim3(NH, NB/64, 3), 256, 0, stream>>>(query, key, value, Wq, Wk, Wv,
                                                   bq, bk, bv, cnt, rows, qb, kb, vb);
    k_update<<<NB*NH, 256, 0, stream>>>(matrix, normal, Ww, bw, dlog, slot, topl,
                                        qb, kb, vb, ob, out_matrix, out_norm);
    k_mergemm<<<dim3(NH, NB/64, DM/64), 256, 0, stream>>>(Wo, cnt, rows, topp, ob,
                                                          contrib);
    k_finalize<<<NB, 256, 0, stream>>>(topi, topp, bo, contrib, out_merged);
}